// Round 1
// baseline (2484.417 us; speedup 1.0000x reference)
//
#include <hip/hip_runtime.h>

#define B_  1024
#define T_  512
#define I_  16
#define H_  50
#define G_  200   // 4*H
#define FC_ 64
#define HP  52    // H padded to multiple of 4 (for float4 LDS reads)

__device__ __forceinline__ float sigm(float x)   { return 1.0f / (1.0f + __expf(-x)); }
__device__ __forceinline__ float tanh_f(float x) { return 1.0f - 2.0f / (1.0f + __expf(2.0f * x)); }

// 2 batch rows per block; thread g<200 owns gate g for both rows, both layers,
// with all weight rows resident in VGPRs. Threads 200..231 prefetch x.
__global__ __launch_bounds__(256, 2) void lstm_fused(
    const float* __restrict__ x,
    const float* __restrict__ w_ih0, const float* __restrict__ w_hh0,
    const float* __restrict__ b_ih0, const float* __restrict__ b_hh0,
    const float* __restrict__ w_ih1, const float* __restrict__ w_hh1,
    const float* __restrict__ b_ih1, const float* __restrict__ b_hh1,
    const float* __restrict__ fc1_w, const float* __restrict__ fc1_b,
    const float* __restrict__ fc2_w, const float* __restrict__ fc2_b,
    float* __restrict__ out)
{
    __shared__ float h0s[2][HP], c0s[2][HP], h1s[2][HP], c1s[2][HP];
    __shared__ float gbuf[2][G_];      // activated gates, reused L0 then L1
    __shared__ float xs[4][2][I_];     // x prefetch ring (distance 2)
    __shared__ float fcb[2][FC_];

    const int tid  = threadIdx.x;
    const int row0 = blockIdx.x * 2;
    const int g    = tid;

    // ---- persistent per-thread weight registers ----
    float w0x[I_], w0h[HP], w1x[HP], w1h[HP];
    float b0 = 0.f, b1 = 0.f;
    if (g < G_) {
        #pragma unroll
        for (int i = 0; i < I_; ++i) w0x[i] = w_ih0[g * I_ + i];
        #pragma unroll
        for (int j = 0; j < HP; ++j) w0h[j] = (j < H_) ? w_hh0[g * H_ + j] : 0.f;
        #pragma unroll
        for (int j = 0; j < HP; ++j) w1x[j] = (j < H_) ? w_ih1[g * H_ + j] : 0.f;
        #pragma unroll
        for (int j = 0; j < HP; ++j) w1h[j] = (j < H_) ? w_hh1[g * H_ + j] : 0.f;
        b0 = b_ih0[g] + b_hh0[g];
        b1 = b_ih1[g] + b_hh1[g];
    }

    // ---- init state (incl. padding -> must be exactly 0, LDS is garbage) ----
    if (tid < 2 * HP) {
        ((float*)h0s)[tid] = 0.f; ((float*)c0s)[tid] = 0.f;
        ((float*)h1s)[tid] = 0.f; ((float*)c1s)[tid] = 0.f;
    }
    // stage x(t=0) and x(t=1)
    if (tid >= G_ && tid < G_ + 32) {
        int t2 = tid - G_; int r = t2 >> 4; int i = t2 & 15;
        const float* xp = x + (size_t)(row0 + r) * T_ * I_ + i;
        xs[0][r][i] = xp[0];
        xs[1][r][i] = xp[I_];
    }
    __syncthreads();

    for (int t = 0; t < T_; ++t) {
        const int buf = t & 3;

        // ---- P0: layer-0 gates (+ x prefetch on idle lanes) ----
        if (g < G_) {
            float a0 = b0, a1 = b0;
            const float* xr0 = xs[buf][0];
            const float* xr1 = xs[buf][1];
            #pragma unroll
            for (int i = 0; i < I_; ++i) { a0 += w0x[i] * xr0[i]; a1 += w0x[i] * xr1[i]; }
            const float4* h40 = (const float4*)h0s[0];
            const float4* h41 = (const float4*)h0s[1];
            #pragma unroll
            for (int jj = 0; jj < HP / 4; ++jj) {
                float4 v0 = h40[jj], v1 = h41[jj];
                a0 += w0h[4*jj+0]*v0.x + w0h[4*jj+1]*v0.y + w0h[4*jj+2]*v0.z + w0h[4*jj+3]*v0.w;
                a1 += w0h[4*jj+0]*v1.x + w0h[4*jj+1]*v1.y + w0h[4*jj+2]*v1.z + w0h[4*jj+3]*v1.w;
            }
            const bool is_t = (g >= 2 * H_) && (g < 3 * H_);
            gbuf[0][g] = is_t ? tanh_f(a0) : sigm(a0);
            gbuf[1][g] = is_t ? tanh_f(a1) : sigm(a1);
        } else if (tid < G_ + 32 && t + 2 < T_) {
            int t2 = tid - G_; int r = t2 >> 4; int i = t2 & 15;
            xs[(t + 2) & 3][r][i] = x[(size_t)(row0 + r) * T_ * I_ + (size_t)(t + 2) * I_ + i];
        }
        __syncthreads();

        // ---- P1: layer-0 cell update ----
        if (tid < 2 * H_) {
            const int r = (tid >= H_) ? 1 : 0;
            const int u = tid - r * H_;
            float c = c0s[r][u];
            c = gbuf[r][u + H_] * c + gbuf[r][u] * gbuf[r][u + 2 * H_];
            c0s[r][u] = c;
            h0s[r][u] = gbuf[r][u + 3 * H_] * tanh_f(c);
        }
        __syncthreads();

        // ---- P2: layer-1 gates ----
        if (g < G_) {
            float a0 = b1, a1 = b1;
            const float4* p00 = (const float4*)h0s[0];
            const float4* p01 = (const float4*)h0s[1];
            const float4* p10 = (const float4*)h1s[0];
            const float4* p11 = (const float4*)h1s[1];
            #pragma unroll
            for (int jj = 0; jj < HP / 4; ++jj) {
                float4 v0 = p00[jj], v1 = p01[jj];
                a0 += w1x[4*jj+0]*v0.x + w1x[4*jj+1]*v0.y + w1x[4*jj+2]*v0.z + w1x[4*jj+3]*v0.w;
                a1 += w1x[4*jj+0]*v1.x + w1x[4*jj+1]*v1.y + w1x[4*jj+2]*v1.z + w1x[4*jj+3]*v1.w;
            }
            #pragma unroll
            for (int jj = 0; jj < HP / 4; ++jj) {
                float4 v0 = p10[jj], v1 = p11[jj];
                a0 += w1h[4*jj+0]*v0.x + w1h[4*jj+1]*v0.y + w1h[4*jj+2]*v0.z + w1h[4*jj+3]*v0.w;
                a1 += w1h[4*jj+0]*v1.x + w1h[4*jj+1]*v1.y + w1h[4*jj+2]*v1.z + w1h[4*jj+3]*v1.w;
            }
            const bool is_t = (g >= 2 * H_) && (g < 3 * H_);
            gbuf[0][g] = is_t ? tanh_f(a0) : sigm(a0);
            gbuf[1][g] = is_t ? tanh_f(a1) : sigm(a1);
        }
        __syncthreads();

        // ---- P3: layer-1 cell update ----
        if (tid < 2 * H_) {
            const int r = (tid >= H_) ? 1 : 0;
            const int u = tid - r * H_;
            float c = c1s[r][u];
            c = gbuf[r][u + H_] * c + gbuf[r][u] * gbuf[r][u + 2 * H_];
            c1s[r][u] = c;
            h1s[r][u] = gbuf[r][u + 3 * H_] * tanh_f(c);
        }
        __syncthreads();
    }

    // ---- FC epilogue: h1s = h2[:, T-1, :] ----
    if (tid < 2 * FC_) {
        const int r = tid >> 6, u = tid & 63;
        float a = fc1_b[u];
        #pragma unroll
        for (int j = 0; j < H_; ++j) a += fc1_w[u * H_ + j] * h1s[r][j];
        fcb[r][u] = fmaxf(a, 0.f);
    }
    __syncthreads();
    if (tid < 2) {
        float a = fc2_b[0];
        #pragma unroll
        for (int j = 0; j < FC_; ++j) a += fc2_w[j] * fcb[tid][j];
        out[row0 + tid] = a;
    }
}

extern "C" void kernel_launch(void* const* d_in, const int* in_sizes, int n_in,
                              void* d_out, int out_size, void* d_ws, size_t ws_size,
                              hipStream_t stream) {
    const float* x     = (const float*)d_in[0];
    const float* w_ih0 = (const float*)d_in[1];
    const float* w_hh0 = (const float*)d_in[2];
    const float* b_ih0 = (const float*)d_in[3];
    const float* b_hh0 = (const float*)d_in[4];
    const float* w_ih1 = (const float*)d_in[5];
    const float* w_hh1 = (const float*)d_in[6];
    const float* b_ih1 = (const float*)d_in[7];
    const float* b_hh1 = (const float*)d_in[8];
    const float* fc1_w = (const float*)d_in[9];
    const float* fc1_b = (const float*)d_in[10];
    const float* fc2_w = (const float*)d_in[11];
    const float* fc2_b = (const float*)d_in[12];
    float* out = (float*)d_out;

    dim3 grid(B_ / 2), block(256);
    hipLaunchKernelGGL(lstm_fused, grid, block, 0, stream,
                       x, w_ih0, w_hh0, b_ih0, b_hh0,
                       w_ih1, w_hh1, b_ih1, b_hh1,
                       fc1_w, fc1_b, fc2_w, fc2_b, out);
}

// Round 2
// 1941.386 us; speedup vs baseline: 1.2797x; 1.2797x over previous
//
#include <hip/hip_runtime.h>

#define B_    1024
#define T_    512
#define I_    16
#define H_    50
#define FC_   64
#define HALFW 28    // half of padded H (56)
#define HP    56    // H padded for float4 reads

__device__ __forceinline__ float sigm(float x)   { return 1.0f / (1.0f + __expf(-x)); }
__device__ __forceinline__ float tanh_f(float x) { return 1.0f - 2.0f / (1.0f + __expf(2.0f * x)); }

// One batch row per block. Lane layout (tid < 400): tid = 8*u + 2*q + s
//   u = LSTM unit (0..49), q = gate (0=i,1=f,2=g,3=o), s = dot-product half.
// All 8 lanes of a unit sit in one wave -> gate exchange via shuffles,
// cell state c replicated in registers, h via ping-pong LDS. 2 barriers/step.
__global__ __launch_bounds__(448, 4) void lstm_fused2(
    const float* __restrict__ x,
    const float* __restrict__ w_ih0, const float* __restrict__ w_hh0,
    const float* __restrict__ b_ih0, const float* __restrict__ b_hh0,
    const float* __restrict__ w_ih1, const float* __restrict__ w_hh1,
    const float* __restrict__ b_ih1, const float* __restrict__ b_hh1,
    const float* __restrict__ fc1_w, const float* __restrict__ fc1_b,
    const float* __restrict__ fc2_w, const float* __restrict__ fc2_b,
    float* __restrict__ out)
{
    __shared__ float h0s[2][HP], h1s[2][HP];
    __shared__ float xs[4][I_];          // x prefetch ring, distance 2

    const int tid  = threadIdx.x;
    const int row  = blockIdx.x;
    const int u    = tid >> 3;
    const int q    = (tid >> 1) & 3;
    const int s    = tid & 1;
    const bool gl  = tid < 400;
    const int g    = q * H_ + u;         // row in 4H weight matrices
    const int base = tid & ~7;           // first lane of this unit's octet

    // ---- persistent per-thread weight registers (92 floats, no spill) ----
    float w0x[8], w0h[HALFW], w1x[HALFW], w1h[HALFW];
    float bias0 = 0.f, bias1 = 0.f;
    if (gl) {
        #pragma unroll
        for (int i = 0; i < 8; ++i) w0x[i] = w_ih0[g * I_ + s * 8 + i];
        #pragma unroll
        for (int j = 0; j < HALFW; ++j) {
            const int jj = s * HALFW + j;
            const bool v = jj < H_;
            w0h[j] = v ? w_hh0[g * H_ + jj] : 0.f;
            w1x[j] = v ? w_ih1[g * H_ + jj] : 0.f;
            w1h[j] = v ? w_hh1[g * H_ + jj] : 0.f;
        }
        if (s == 0) {                    // bias counted once per gate pair
            bias0 = b_ih0[g] + b_hh0[g];
            bias1 = b_ih1[g] + b_hh1[g];
        }
    }

    if (tid < HP) {                      // zero h (incl. padding)
        h0s[0][tid] = 0.f; h0s[1][tid] = 0.f;
        h1s[0][tid] = 0.f; h1s[1][tid] = 0.f;
    }
    if (tid < 8) {                       // stage x(0), x(1)
        const int tt = tid >> 2, i4 = (tid & 3) * 4;
        *(float4*)&xs[tt][i4] = *(const float4*)(x + ((size_t)row * T_ + tt) * I_ + i4);
    }
    float c0 = 0.f, c1 = 0.f;
    __syncthreads();

    for (int t = 0; t < T_; ++t) {
        const int p = t & 1;             // read h*[p], write h*[1-p]

        // ---- P0: layer-0 gates + cell update (x prefetch on idle lanes) ----
        if (gl) {
            float a = bias0, b2 = 0.f;
            const float4* xp = (const float4*)(xs[t & 3] + s * 8);
            float4 v0 = xp[0], v1 = xp[1];
            a  += w0x[0]*v0.x + w0x[1]*v0.y + w0x[2]*v0.z + w0x[3]*v0.w;
            b2 += w0x[4]*v1.x + w0x[5]*v1.y + w0x[6]*v1.z + w0x[7]*v1.w;
            const float4* hp = (const float4*)(h0s[p] + s * HALFW);
            #pragma unroll
            for (int k = 0; k < 7; ++k) {
                float4 hv = hp[k];
                if (k & 1) b2 += w0h[4*k]*hv.x + w0h[4*k+1]*hv.y + w0h[4*k+2]*hv.z + w0h[4*k+3]*hv.w;
                else       a  += w0h[4*k]*hv.x + w0h[4*k+1]*hv.y + w0h[4*k+2]*hv.z + w0h[4*k+3]*hv.w;
            }
            float pre = a + b2;
            pre += __shfl_xor(pre, 1);                       // join halves
            const float act = (q == 2) ? tanh_f(pre) : sigm(pre);
            const float gi = __shfl(act, base);
            const float gf = __shfl(act, base + 2);
            const float gg = __shfl(act, base + 4);
            const float go = __shfl(act, base + 6);
            c0 = gf * c0 + gi * gg;
            if ((tid & 7) == 0) h0s[1 - p][u] = go * tanh_f(c0);
        } else if (tid >= 432 && tid < 436) {
            if (t + 2 < T_) {
                const int i4 = (tid - 432) * 4;
                *(float4*)&xs[(t + 2) & 3][i4] =
                    *(const float4*)(x + ((size_t)row * T_ + t + 2) * I_ + i4);
            }
        }
        __syncthreads();

        // ---- P1: layer-1 gates + cell update ----
        if (gl) {
            float a = bias1, b2 = 0.f;
            const float4* h0p = (const float4*)(h0s[1 - p] + s * HALFW);
            const float4* h1p = (const float4*)(h1s[p]     + s * HALFW);
            #pragma unroll
            for (int k = 0; k < 7; ++k) {
                float4 hv = h0p[k];
                if (k & 1) b2 += w1x[4*k]*hv.x + w1x[4*k+1]*hv.y + w1x[4*k+2]*hv.z + w1x[4*k+3]*hv.w;
                else       a  += w1x[4*k]*hv.x + w1x[4*k+1]*hv.y + w1x[4*k+2]*hv.z + w1x[4*k+3]*hv.w;
            }
            #pragma unroll
            for (int k = 0; k < 7; ++k) {
                float4 hv = h1p[k];
                if (k & 1) b2 += w1h[4*k]*hv.x + w1h[4*k+1]*hv.y + w1h[4*k+2]*hv.z + w1h[4*k+3]*hv.w;
                else       a  += w1h[4*k]*hv.x + w1h[4*k+1]*hv.y + w1h[4*k+2]*hv.z + w1h[4*k+3]*hv.w;
            }
            float pre = a + b2;
            pre += __shfl_xor(pre, 1);
            const float act = (q == 2) ? tanh_f(pre) : sigm(pre);
            const float gi = __shfl(act, base);
            const float gf = __shfl(act, base + 2);
            const float gg = __shfl(act, base + 4);
            const float go = __shfl(act, base + 6);
            c1 = gf * c1 + gi * gg;
            if ((tid & 7) == 0) h1s[1 - p][u] = go * tanh_f(c1);
        }
        __syncthreads();
    }

    // ---- FC epilogue: final h1 is in h1s[0] (T even) ----
    if (tid < FC_) {
        const float* hf = h1s[0];
        float a = fc1_b[tid];
        #pragma unroll
        for (int j = 0; j < H_; ++j) a += fc1_w[tid * H_ + j] * hf[j];
        float r = fmaxf(a, 0.f) * fc2_w[tid];
        #pragma unroll
        for (int off = 1; off < FC_; off <<= 1) r += __shfl_xor(r, off);
        if (tid == 0) out[row] = r + fc2_b[0];
    }
}

extern "C" void kernel_launch(void* const* d_in, const int* in_sizes, int n_in,
                              void* d_out, int out_size, void* d_ws, size_t ws_size,
                              hipStream_t stream) {
    const float* x     = (const float*)d_in[0];
    const float* w_ih0 = (const float*)d_in[1];
    const float* w_hh0 = (const float*)d_in[2];
    const float* b_ih0 = (const float*)d_in[3];
    const float* b_hh0 = (const float*)d_in[4];
    const float* w_ih1 = (const float*)d_in[5];
    const float* w_hh1 = (const float*)d_in[6];
    const float* b_ih1 = (const float*)d_in[7];
    const float* b_hh1 = (const float*)d_in[8];
    const float* fc1_w = (const float*)d_in[9];
    const float* fc1_b = (const float*)d_in[10];
    const float* fc2_w = (const float*)d_in[11];
    const float* fc2_b = (const float*)d_in[12];
    float* out = (float*)d_out;

    dim3 grid(B_), block(448);
    hipLaunchKernelGGL(lstm_fused2, grid, block, 0, stream,
                       x, w_ih0, w_hh0, b_ih0, b_hh0,
                       w_ih1, w_hh1, b_ih1, b_hh1,
                       fc1_w, fc1_b, fc2_w, fc2_b, out);
}